// Round 4
// baseline (192.080 us; speedup 1.0000x reference)
//
#include <hip/hip_runtime.h>
#include <hip/hip_bf16.h>

// Mex forward: B=64,C=64,H=W=64, BLK=(64,3,3), STR=(64,2,2), PAD=(0,1,1),
// NI=256, EPS=1, mean mode. OH=OW=32, K=576, out (64,256,32,32) fp32.
//
// y[n][i] = log( sum_k exp(P[n][k] + O[i][k]) ) - log(576)
// Shift-invariant -> no max pass. Zero-padded entries -> exp(0)=1.
//
// Pipeline:
//   1) mex_exp_tr : E[b][h][w][c] = bf16(exp(x)), register-direct transpose,
//                   chunk stored at c8 ^ ((w>>1)&7) (bank swizzle pre-baked).
//                   XCD-congruent block map. Also folds Bt prep (blocks 0-63).
//   2) mex_main   : one oh-ROW per block (M=32, 2048 blocks, 25.3 KB LDS,
//                   ~92 unified regs -> 5 blocks/CU = 20 waves/CU). DMA 3
//                   E-rows into LDS, one barrier, 18-step barrier-free
//                   MFMA K-loop (2 m-tiles x 4 n-tiles per wave).

typedef __bf16 bf16x8 __attribute__((ext_vector_type(8)));
typedef float  f32x4  __attribute__((ext_vector_type(4)));

#define GLD16(gp, lp) __builtin_amdgcn_global_load_lds(                        \
    (const __attribute__((address_space(1))) unsigned int*)(gp),               \
    (__attribute__((address_space(3))) unsigned int*)(lp), 16, 0, 0)

// ---- E transform (+ folded Bt prep) ---------------------------------------
// 1024 blocks = 128 t x 8 x8;  b = t>>1, half = t&1, g8 = (x8-b)&7,
// h-range = (g8*2+half)*4 .. +4.  Lane = w; task (hh,c8) -> 8 coalesced
// c-strided loads give this lane exactly chunk (w, c8). No LDS.
__global__ __launch_bounds__(256) void mex_exp_tr(
        const float* __restrict__ x, const float* __restrict__ off,
        __bf16* __restrict__ E, __bf16* __restrict__ Bt) {
    const int bid = blockIdx.x;
    const int x8 = bid & 7, t = bid >> 3;
    const int b = t >> 1, half = t & 1;
    const int g8 = (x8 - b) & 7;
    const int h0 = (g8 * 2 + half) * 4;
    const int lane = threadIdx.x & 63;
    const int wv   = threadIdx.x >> 6;

    if (bid < 64) {   // folded prep_b: Bt[i][p*64+c] = exp(off[i][c*9+p])
        const int i = bid * 4 + wv;
        const float* oi = off + i * 576;
        __bf16* bi = Bt + i * 576;
        #pragma unroll
        for (int p = 0; p < 9; ++p)
            bi[p * 64 + lane] = (__bf16)__expf(oi[lane * 9 + p]);
    }

    #pragma unroll 2
    for (int tt = 0; tt < 8; ++tt) {
        const int task = tt * 4 + wv;          // 32 tasks: (hh 0..3, c8 0..7)
        const int hh = task >> 3, c8 = task & 7;
        const int h  = h0 + hh;
        const float* xp = x + (((size_t)(b * 64 + c8 * 8)) << 12) + (h << 6) + lane;
        float v[8];
        #pragma unroll
        for (int j = 0; j < 8; ++j) v[j] = xp[(size_t)j << 12];
        bf16x8 o;
        #pragma unroll
        for (int j = 0; j < 8; ++j) o[j] = (__bf16)__expf(v[j]);
        const int c8p = c8 ^ ((lane >> 1) & 7);   // baked swizzle
        *(bf16x8*)(E + (((size_t)(b * 64 + h)) << 12) + (lane << 6) + (c8p << 3)) = o;
    }
}

// ---- main fused kernel ----------------------------------------------------
__global__ __launch_bounds__(256, 5) void mex_main(
        const __bf16* __restrict__ E,
        const __bf16* __restrict__ Bt,
        float* __restrict__ out) {
    // [hl 0..2][w_idx 0..65][chunk 0..7] bf16x8; w_idx = w_global+1. 25344 B.
    __shared__ bf16x8 lds8[3 * 66 * 8];

    // bid = t*8 + x8; b = t>>2, s = t&3, g = (x8-b)&7, oh = g*4+s
    // -> staging rows (hg ~ 2oh) live on XCD x8 (written there by exp_tr)
    const int bid = blockIdx.x;      // 0..2047
    const int x8  = bid & 7;
    const int t   = bid >> 3;
    const int b   = t >> 2;
    const int g   = (x8 - b) & 7;
    const int oh  = g * 4 + (t & 3); // 0..31

    const int tid  = threadIdx.x;
    const int lane = tid & 63;
    const int wv   = tid >> 6;
    const int t16  = tid & 15;
    const int q    = (tid >> 4) & 3;

    // ---- B fragment first loads (overlap under the staging barrier) ------
    const bf16x8* __restrict__ Btv = (const bf16x8*)Bt;  // 72 chunks / inst
    const int instRow = (wv * 64 + t16) * 72 + q;
    bf16x8 bcur[4];
    #pragma unroll
    for (int nt = 0; nt < 4; ++nt)
        bcur[nt] = Btv[instRow + nt * (16 * 72)];

    // ---- pad fills (LDS stores) ------------------------------------------
    bf16x8 one8;
    #pragma unroll
    for (int j = 0; j < 8; ++j) one8[j] = (__bf16)1.0f;
    if (tid < 24) {                  // w_idx = 0 column (w_global = -1)
        const int hl = tid >> 3, cc = tid & 7;
        lds8[(hl * 66) * 8 + cc] = one8;
    }
    if (oh == 0) {                   // h_global = -1 -> whole hl=0 row = ones
        for (int i = tid; i < 66 * 8; i += 256) lds8[i] = one8;
    }

    // ---- async DMA: 24 segments of 1 KB, 6 per wave ----------------------
    #pragma unroll
    for (int s = 0; s < 6; ++s) {
        const int seg = wv * 6 + s;
        const int hl = seg >> 3, sg = seg & 7;
        const int hg = 2 * oh - 1 + hl;            // -1..63
        if (hg >= 0) {                             // wave-uniform predicate
            const __bf16* gp = E + (((size_t)b * 64 + hg) << 12) + (sg << 9) + (lane << 3);
            bf16x8* lp = lds8 + hl * 528 + 8 + sg * 64;   // uniform base
            GLD16(gp, lp);
        }
    }
    __syncthreads();   // drains staging DMA + bcur; the only barrier

    int rbase[2], owv[2];
    #pragma unroll
    for (int mt = 0; mt < 2; ++mt) {
        const int m = mt * 16 + t16;   // = ow
        owv[mt]   = m;
        rbase[mt] = m * 2;
    }

    f32x4 acc[2][4];
    #pragma unroll
    for (int mt = 0; mt < 2; ++mt)
        #pragma unroll
        for (int nt = 0; nt < 4; ++nt)
            acc[mt][nt] = (f32x4)(0.0f);

    #pragma unroll 2
    for (int ks = 0; ks < 18; ++ks) {
        const int p  = ks >> 1;
        const int fh = (p * 11) >> 5;              // p/3
        const int fw = p - fh * 3;
        const int rofs = fh * 66 + fw;
        const int ccq  = ((ks & 1) << 2) + q;

        bf16x8 a[2];
        #pragma unroll
        for (int mt = 0; mt < 2; ++mt) {
            const int row = rbase[mt] + rofs;      // hl*66 + w_idx
            const int key = ((owv[mt] * 2 + fw - 1) >> 1) & 7;  // w-only swizzle
            a[mt] = lds8[row * 8 + (ccq ^ key)];
        }

        bf16x8 bnext[4];
        if (ks < 17) {
            #pragma unroll
            for (int nt = 0; nt < 4; ++nt)
                bnext[nt] = Btv[instRow + nt * (16 * 72) + (ks + 1) * 4];
        }

        #pragma unroll
        for (int mt = 0; mt < 2; ++mt)
            #pragma unroll
            for (int nt = 0; nt < 4; ++nt)
                acc[mt][nt] = __builtin_amdgcn_mfma_f32_16x16x32_bf16(
                    a[mt], bcur[nt], acc[mt][nt], 0, 0, 0);

        #pragma unroll
        for (int nt = 0; nt < 4; ++nt) bcur[nt] = bnext[nt];
    }

    // ---- epilogue: y = log(S) - log(576) ---------------------------------
    const float lK = 6.356107660695891f;   // log(576)
    #pragma unroll
    for (int mt = 0; mt < 2; ++mt) {
        const int m = mt * 16 + (q << 2);          // C/D: row = q*4 + reg = ow
        const int orow = oh * 32 + m;
        #pragma unroll
        for (int nt = 0; nt < 4; ++nt) {
            const int inst = wv * 64 + nt * 16 + t16;   // C/D: col = lane&15
            f32x4 r;
            #pragma unroll
            for (int j = 0; j < 4; ++j)
                r[j] = __logf(acc[mt][nt][j]) - lK;
            *(f32x4*)(out + (((size_t)b * 256 + inst) * 1024 + orow)) = r;
        }
    }
}

extern "C" void kernel_launch(void* const* d_in, const int* in_sizes, int n_in,
                              void* d_out, int out_size, void* d_ws, size_t ws_size,
                              hipStream_t stream) {
    const float* x   = (const float*)d_in[0];   // (64,64,64,64) fp32
    const float* off = (const float*)d_in[1];   // (1,256,64,3,3) fp32
    float* out = (float*)d_out;                 // (64,256,32,32) fp32
    __bf16* E  = (__bf16*)d_ws;                 // 64*64*64*64*2 = 33554432 B
    __bf16* Bt = (__bf16*)((char*)d_ws + 33554432);   // 294912 B

    mex_exp_tr<<<1024, 256, 0, stream>>>(x, off, E, Bt);
    mex_main<<<2048, 256, 0, stream>>>(E, Bt, out);
}

// Round 5
// 189.220 us; speedup vs baseline: 1.0151x; 1.0151x over previous
//
#include <hip/hip_runtime.h>
#include <hip/hip_bf16.h>

// Mex forward: B=64,C=64,H=W=64, BLK=(64,3,3), STR=(64,2,2), PAD=(0,1,1),
// NI=256, EPS=1, mean mode. OH=OW=32, K=576, out (64,256,32,32) fp32.
//
// y[n][i] = log( sum_k exp(P[n][k] + O[i][k]) ) - log(576)
// Shift-invariant -> no max pass. Zero-padded entries -> exp(0)=1.
//
// Pipeline:
//   1) mex_exp_tr : E[b][h][w][c] = bf16(exp(x)), register-direct transpose,
//                   chunk stored at c8 ^ ((w>>1)&7) (bank swizzle pre-baked).
//                   XCD-congruent block map. Folds Bt prep (blocks 0-63).
//   2) mex_main   : PERSISTENT over 2 tiles. 512 blocks = (b, h-group g8),
//                   XCD-congruent. Tile = 2 oh-rows (M=64, 5 E-rows, 42 KB
//                   LDS, single buffer). Next tile's E prefetched into
//                   REGISTERS (10 x bf16x8/thread) during current tile's
//                   K-loop -> stage latency hidden under MFMA compute
//                   instead of drained at the barrier (the R1-R4 stall).

typedef __bf16 bf16x8 __attribute__((ext_vector_type(8)));
typedef float  f32x4  __attribute__((ext_vector_type(4)));

// ---- E transform (+ folded Bt prep) ---------------------------------------
__global__ __launch_bounds__(256) void mex_exp_tr(
        const float* __restrict__ x, const float* __restrict__ off,
        __bf16* __restrict__ E, __bf16* __restrict__ Bt) {
    const int bid = blockIdx.x;
    const int x8 = bid & 7, t = bid >> 3;
    const int b = t >> 1, half = t & 1;
    const int g8 = (x8 - b) & 7;
    const int h0 = (g8 * 2 + half) * 4;
    const int lane = threadIdx.x & 63;
    const int wv   = threadIdx.x >> 6;

    if (bid < 64) {   // folded prep_b: Bt[i][p*64+c] = exp(off[i][c*9+p])
        const int i = bid * 4 + wv;
        const float* oi = off + i * 576;
        __bf16* bi = Bt + i * 576;
        #pragma unroll
        for (int p = 0; p < 9; ++p)
            bi[p * 64 + lane] = (__bf16)__expf(oi[lane * 9 + p]);
    }

    #pragma unroll 2
    for (int tt = 0; tt < 8; ++tt) {
        const int task = tt * 4 + wv;          // 32 tasks: (hh 0..3, c8 0..7)
        const int hh = task >> 3, c8 = task & 7;
        const int h  = h0 + hh;
        const float* xp = x + (((size_t)(b * 64 + c8 * 8)) << 12) + (h << 6) + lane;
        float v[8];
        #pragma unroll
        for (int j = 0; j < 8; ++j) v[j] = xp[(size_t)j << 12];
        bf16x8 o;
        #pragma unroll
        for (int j = 0; j < 8; ++j) o[j] = (__bf16)__expf(v[j]);
        const int c8p = c8 ^ ((lane >> 1) & 7);   // baked swizzle
        *(bf16x8*)(E + (((size_t)(b * 64 + h)) << 12) + (lane << 6) + (c8p << 3)) = o;
    }
}

// ---- main fused kernel ----------------------------------------------------
__global__ __launch_bounds__(256, 3) void mex_main(
        const __bf16* __restrict__ E,
        const __bf16* __restrict__ Bt,
        float* __restrict__ out) {
    // [hl 0..4][w_idx 0..65][chunk 0..7] bf16x8; w_idx = w_global+1. 42240 B.
    __shared__ bf16x8 lds8[5 * 66 * 8];

    // 512 blocks: bid = b*8 + ((g8+b)&7); block owns h-group g8 (rows
    // 8g8-1..8g8+7) on XCD (b+g8)&7 = exp_tr's writer XCD. Tiles e=0,1:
    // oh0 = g8*4 + 2e.
    const int bid = blockIdx.x;
    const int b   = bid >> 3;
    const int g8  = ((bid & 7) - b) & 7;

    const int tid  = threadIdx.x;
    const int lane = tid & 63;
    const int wv   = tid >> 6;
    const int t16  = tid & 15;
    const int q    = (tid >> 4) & 3;

    bf16x8 one8;
    #pragma unroll
    for (int j = 0; j < 8; ++j) one8[j] = (__bf16)1.0f;

    // ---- prefetch tile e=0 into registers --------------------------------
    bf16x8 val[10];
    {
        const int oh0 = g8 * 4;
        #pragma unroll
        for (int i = 0; i < 10; ++i) {
            const int seg = i * 4 + wv, hl = seg >> 3, sg = seg & 7;
            const int hg = 2 * oh0 - 1 + hl;
            if (hg >= 0)
                val[i] = *(const bf16x8*)(E + (((size_t)b * 64 + hg) << 12) + (sg << 9) + (lane << 3));
            else
                val[i] = one8;                 // h = -1 pad row
        }
    }

    // w_idx = 0 pad column (w_global = -1): written once, never overwritten
    if (tid < 40) {
        const int hl = tid >> 3, cc = tid & 7;
        lds8[(hl * 66) * 8 + cc] = one8;
    }

    const bf16x8* __restrict__ Btv = (const bf16x8*)Bt;  // 72 chunks / inst
    const int instRow = (wv * 64 + t16) * 72 + q;

    int rbase[4], owv[4];
    #pragma unroll
    for (int mt = 0; mt < 4; ++mt) {
        const int m = mt * 16 + t16;
        owv[mt]   = m & 31;
        rbase[mt] = ((m >> 5) * 132) + ((m & 31) * 2);
    }

    #pragma unroll 1
    for (int e = 0; e < 2; ++e) {
        const int oh0 = g8 * 4 + e * 2;

        // ---- staged regs -> LDS ------------------------------------------
        #pragma unroll
        for (int i = 0; i < 10; ++i) {
            const int seg = i * 4 + wv, hl = seg >> 3, sg = seg & 7;
            lds8[hl * 528 + 8 + sg * 64 + lane] = val[i];
        }
        __syncthreads();

        // ---- bcur first (so its vmcnt wait doesn't cover the prefetch) ---
        bf16x8 bcur[4];
        #pragma unroll
        for (int nt = 0; nt < 4; ++nt)
            bcur[nt] = Btv[instRow + nt * (16 * 72)];

        // ---- prefetch NEXT tile's E into regs (hidden under K-loop) ------
        if (e == 0) {
            const int noh0 = g8 * 4 + 2;
            #pragma unroll
            for (int i = 0; i < 10; ++i) {
                const int seg = i * 4 + wv, hl = seg >> 3, sg = seg & 7;
                const int hg = 2 * noh0 - 1 + hl;   // >= 3 always
                val[i] = *(const bf16x8*)(E + (((size_t)b * 64 + hg) << 12) + (sg << 9) + (lane << 3));
            }
        }

        f32x4 acc[4][4];
        #pragma unroll
        for (int mt = 0; mt < 4; ++mt)
            #pragma unroll
            for (int nt = 0; nt < 4; ++nt)
                acc[mt][nt] = (f32x4)(0.0f);

        #pragma unroll 2
        for (int ks = 0; ks < 18; ++ks) {
            const int p  = ks >> 1;
            const int fh = (p * 11) >> 5;          // p/3
            const int fw = p - fh * 3;
            const int rofs = fh * 66 + fw;
            const int ccq  = ((ks & 1) << 2) + q;

            bf16x8 a[4];
            #pragma unroll
            for (int mt = 0; mt < 4; ++mt) {
                const int row = rbase[mt] + rofs;  // hl*66 + w_idx
                const int key = ((owv[mt] * 2 + fw - 1) >> 1) & 7;
                a[mt] = lds8[row * 8 + (ccq ^ key)];
            }

            bf16x8 bnext[4];
            if (ks < 17) {
                #pragma unroll
                for (int nt = 0; nt < 4; ++nt)
                    bnext[nt] = Btv[instRow + nt * (16 * 72) + (ks + 1) * 4];
            }

            #pragma unroll
            for (int mt = 0; mt < 4; ++mt)
                #pragma unroll
                for (int nt = 0; nt < 4; ++nt)
                    acc[mt][nt] = __builtin_amdgcn_mfma_f32_16x16x32_bf16(
                        a[mt], bcur[nt], acc[mt][nt], 0, 0, 0);

            #pragma unroll
            for (int nt = 0; nt < 4; ++nt) bcur[nt] = bnext[nt];
        }

        // ---- epilogue: y = log(S) - log(576) -----------------------------
        const float lK = 6.356107660695891f;       // log(576)
        #pragma unroll
        for (int mt = 0; mt < 4; ++mt) {
            const int m   = mt * 16 + (q << 2);    // C/D: row = q*4 + reg
            const int ohl = m >> 5;
            const int owi = m & 31;
            const int orow = (oh0 + ohl) * 32 + owi;
            #pragma unroll
            for (int nt = 0; nt < 4; ++nt) {
                const int inst = wv * 64 + nt * 16 + t16;  // C/D: col = lane&15
                f32x4 r;
                #pragma unroll
                for (int j = 0; j < 4; ++j)
                    r[j] = __logf(acc[mt][nt][j]) - lK;
                *(f32x4*)(out + (((size_t)b * 256 + inst) * 1024 + orow)) = r;
            }
        }

        if (e == 0) __syncthreads();   // all waves done reading LDS tile 0
    }
}

extern "C" void kernel_launch(void* const* d_in, const int* in_sizes, int n_in,
                              void* d_out, int out_size, void* d_ws, size_t ws_size,
                              hipStream_t stream) {
    const float* x   = (const float*)d_in[0];   // (64,64,64,64) fp32
    const float* off = (const float*)d_in[1];   // (1,256,64,3,3) fp32
    float* out = (float*)d_out;                 // (64,256,32,32) fp32
    __bf16* E  = (__bf16*)d_ws;                 // 64*64*64*64*2 = 33554432 B
    __bf16* Bt = (__bf16*)((char*)d_ws + 33554432);   // 294912 B

    mex_exp_tr<<<1024, 256, 0, stream>>>(x, off, E, Bt);
    mex_main<<<512, 256, 0, stream>>>(E, Bt, out);
}